// Round 1
// baseline (499.707 us; speedup 1.0000x reference)
//
#include <hip/hip_runtime.h>
#include <math.h>

#define T_SEQ 2048
#define D_MODEL 1024
#define DH 128

// ---------------- Kernel A: QKV projection + fused RoPE ----------------
// Q[m][h] = sum_d x[m][d] * W[h][d]   (W is [128][1024] row-major)
// grid: (M/64, 3)  block: 256.  Output planes: Q | K | V, each [M][128] fp32 in ws.
__global__ __launch_bounds__(256) void qkv_rope_kernel(
    const float* __restrict__ x,
    const float* __restrict__ Wq,
    const float* __restrict__ Wk,
    const float* __restrict__ Wv,
    const float* __restrict__ theta,
    float* __restrict__ qkv, int M)
{
    // transposed staging: [k][row]; strides 72/136 floats -> 288/544 B rows (16B aligned)
    __shared__ float Xs[32][72];
    __shared__ float Ws[32][136];

    const int m0 = blockIdx.x * 64;
    const int wsel = blockIdx.y;
    const float* W = (wsel == 0) ? Wq : (wsel == 1) ? Wk : Wv;
    float* dst = qkv + (size_t)wsel * M * DH;

    const int tid = threadIdx.x;
    const int h0  = (tid & 15) * 8;   // 8 consecutive h (RoPE pairs stay in-thread)
    const int qq0 = (tid >> 4) * 4;   // 4 rows

    float acc[4][8];
    #pragma unroll
    for (int i = 0; i < 4; ++i)
        #pragma unroll
        for (int j = 0; j < 8; ++j) acc[i][j] = 0.f;

    for (int kc = 0; kc < D_MODEL; kc += 32) {
        __syncthreads();  // previous compute done before overwriting LDS
        for (int i = tid; i < 512; i += 256) {          // 64 rows x 32 cols of x
            int row = i >> 3;
            int c   = (i & 7) * 4;
            float4 v = *(const float4*)(x + (size_t)(m0 + row) * D_MODEL + kc + c);
            Xs[c+0][row] = v.x; Xs[c+1][row] = v.y; Xs[c+2][row] = v.z; Xs[c+3][row] = v.w;
        }
        for (int i = tid; i < 1024; i += 256) {         // 128 rows x 32 cols of W
            int row = i >> 3;
            int c   = (i & 7) * 4;
            float4 v = *(const float4*)(W + (size_t)row * D_MODEL + kc + c);
            Ws[c+0][row] = v.x; Ws[c+1][row] = v.y; Ws[c+2][row] = v.z; Ws[c+3][row] = v.w;
        }
        __syncthreads();
        #pragma unroll 8
        for (int k = 0; k < 32; ++k) {
            float4 xv = *(const float4*)&Xs[k][qq0];
            float4 wa = *(const float4*)&Ws[k][h0];
            float4 wb = *(const float4*)&Ws[k][h0 + 4];
            float xr[4] = {xv.x, xv.y, xv.z, xv.w};
            float wr[8] = {wa.x, wa.y, wa.z, wa.w, wb.x, wb.y, wb.z, wb.w};
            #pragma unroll
            for (int i = 0; i < 4; ++i)
                #pragma unroll
                for (int j = 0; j < 8; ++j)
                    acc[i][j] = fmaf(xr[i], wr[j], acc[i][j]);
        }
    }

    // epilogue: RoPE for Q,K (wsel<2); V stored raw.
    // ref: out_even = e*cos + o*sin ; out_odd = o*cos - e*sin ; ang = (t+1)*theta[h]
    #pragma unroll
    for (int i = 0; i < 4; ++i) {
        int m = m0 + qq0 + i;
        int t = m & (T_SEQ - 1);
        float pos = (float)(t + 1);
        float vals[8];
        if (wsel < 2) {
            #pragma unroll
            for (int p = 0; p < 4; ++p) {
                float ang = pos * theta[h0 + 2 * p];
                float s, c;
                sincosf(ang, &s, &c);
                float e = acc[i][2*p], o = acc[i][2*p+1];
                vals[2*p]   = e * c + o * s;
                vals[2*p+1] = o * c - e * s;
            }
        } else {
            #pragma unroll
            for (int j = 0; j < 8; ++j) vals[j] = acc[i][j];
        }
        *(float4*)(dst + (size_t)m * DH + h0)     = make_float4(vals[0], vals[1], vals[2], vals[3]);
        *(float4*)(dst + (size_t)m * DH + h0 + 4) = make_float4(vals[4], vals[5], vals[6], vals[7]);
    }
}

// ---------------- Kernel B: causal flash attention ----------------
// QT=16 q-rows per tile, KT=32 k-rows per tile, 256 threads.
// Each block handles q-tile pair {bx, 127-bx} -> ~65 k-tiles per block (balanced).
#define QT 16
#define KT 32

__global__ __launch_bounds__(256) void attn_kernel(
    const float* __restrict__ qkv, float* __restrict__ out, int M)
{
    __shared__ float Qs[QT][132];   // 528B rows: 16B aligned, bank offset 4/row
    __shared__ float Ks[KT][132];
    __shared__ float Vs[KT][132];
    __shared__ float Ss[QT][36];

    const int b = blockIdx.y;
    const float* Qp = qkv + (size_t)b * T_SEQ * DH;
    const float* Kp = qkv + (size_t)M * DH + (size_t)b * T_SEQ * DH;
    const float* Vp = qkv + 2 * (size_t)M * DH + (size_t)b * T_SEQ * DH;

    const int tid  = threadIdx.x;
    const int qrow = tid >> 4;        // 0..15 (16 lanes per row -> intra-wave groups)
    const int lk   = tid & 15;        // k-lane within row group
    const int d0   = (tid & 15) * 8;  // 8 output dims per thread

    for (int pass = 0; pass < 2; ++pass) {
        const int qt = pass ? (127 - (int)blockIdx.x) : (int)blockIdx.x;
        const int q0 = qt * QT;

        __syncthreads();  // pass 1: score reads of old Qs done before overwrite
        for (int i = tid; i < QT * 32; i += 256) {
            int row = i >> 5;
            int c   = (i & 31) * 4;
            *(float4*)&Qs[row][c] = *(const float4*)(Qp + (size_t)(q0 + row) * DH + c);
        }

        float m = -INFINITY, l = 0.f;
        float O[8];
        #pragma unroll
        for (int e = 0; e < 8; ++e) O[e] = 0.f;

        const int ktmax = q0 >> 5;    // last (diagonal) k-tile index
        for (int kt = 0; kt <= ktmax; ++kt) {
            const int k0 = kt * KT;
            __syncthreads();  // prev PV reads of Ks/Vs done
            for (int i = tid; i < KT * 32; i += 256) {
                int row = i >> 5;
                int c   = (i & 31) * 4;
                *(float4*)&Ks[row][c] = *(const float4*)(Kp + (size_t)(k0 + row) * DH + c);
                *(float4*)&Vs[row][c] = *(const float4*)(Vp + (size_t)(k0 + row) * DH + c);
            }
            __syncthreads();

            // scores: this thread owns (qrow, k = k0+lk and k0+lk+16)
            float sc[2] = {0.f, 0.f};
            #pragma unroll 8
            for (int d = 0; d < DH; d += 4) {
                float4 qv = *(const float4*)&Qs[qrow][d];
                #pragma unroll
                for (int j = 0; j < 2; ++j) {
                    float4 kv = *(const float4*)&Ks[lk + 16 * j][d];
                    sc[j] += qv.x * kv.x + qv.y * kv.y + qv.z * kv.z + qv.w * kv.w;
                }
            }
            const int qg = q0 + qrow;
            float tmax = -INFINITY;
            #pragma unroll
            for (int j = 0; j < 2; ++j) {
                int kg = k0 + lk + 16 * j;
                sc[j] = (kg <= qg) ? sc[j] * 0.03125f : -1e30f;  // scale = 1024^-0.5
                tmax = fmaxf(tmax, sc[j]);
            }
            #pragma unroll
            for (int off = 1; off < 16; off <<= 1)
                tmax = fmaxf(tmax, __shfl_xor(tmax, off, 64));
            const float mnew  = fmaxf(m, tmax);
            const float alpha = __expf(m - mnew);   // expf(-inf)=0 on first tile
            float psum = 0.f;
            #pragma unroll
            for (int j = 0; j < 2; ++j) {
                float p = __expf(sc[j] - mnew);
                Ss[qrow][lk + 16 * j] = p;
                psum += p;
            }
            #pragma unroll
            for (int off = 1; off < 16; off <<= 1)
                psum += __shfl_xor(psum, off, 64);
            l = l * alpha + psum;
            m = mnew;
            #pragma unroll
            for (int e = 0; e < 8; ++e) O[e] *= alpha;
            __syncthreads();  // Ss writes visible (also orders vs next-tile overwrite)

            // PV: O[qrow][d0..d0+7] += sum_k P[qrow][k] * V[k][d0..]
            #pragma unroll 4
            for (int k = 0; k < KT; ++k) {
                const float p = Ss[qrow][k];
                float4 v0 = *(const float4*)&Vs[k][d0];
                float4 v1 = *(const float4*)&Vs[k][d0 + 4];
                float vv[8] = {v0.x, v0.y, v0.z, v0.w, v1.x, v1.y, v1.z, v1.w};
                #pragma unroll
                for (int e = 0; e < 8; ++e) O[e] = fmaf(p, vv[e], O[e]);
            }
        }

        const float rl = 1.f / l;
        float* orow = out + ((size_t)b * T_SEQ + q0 + qrow) * DH + d0;
        *(float4*)orow       = make_float4(O[0]*rl, O[1]*rl, O[2]*rl, O[3]*rl);
        *(float4*)(orow + 4) = make_float4(O[4]*rl, O[5]*rl, O[6]*rl, O[7]*rl);
    }
}

extern "C" void kernel_launch(void* const* d_in, const int* in_sizes, int n_in,
                              void* d_out, int out_size, void* d_ws, size_t ws_size,
                              hipStream_t stream) {
    const float* x     = (const float*)d_in[0];
    const float* Wq    = (const float*)d_in[1];
    const float* Wk    = (const float*)d_in[2];
    const float* Wv    = (const float*)d_in[3];
    const float* theta = (const float*)d_in[4];
    float* out = (float*)d_out;
    float* qkv = (float*)d_ws;   // needs 3*M*128*4 = 12.6 MB

    const int M = in_sizes[0] / D_MODEL;   // B*T = 8192
    const int B = M / T_SEQ;               // 4

    qkv_rope_kernel<<<dim3(M / 64, 3), 256, 0, stream>>>(x, Wq, Wk, Wv, theta, qkv, M);
    attn_kernel<<<dim3((T_SEQ / QT) / 2, B), 256, 0, stream>>>(qkv, out, M);
}

// Round 2
// 214.622 us; speedup vs baseline: 2.3283x; 2.3283x over previous
//
#include <hip/hip_runtime.h>
#include <math.h>

#define T_SEQ 2048
#define D_MODEL 1024
#define DH 128

typedef __bf16 bfx8 __attribute__((ext_vector_type(8)));
typedef float f32x4 __attribute__((ext_vector_type(4)));

union U16x8 { uint4 u4; unsigned short us[8]; __bf16 bf[8]; };

__device__ inline uint4 cvt8(float4 a, float4 b) {
    U16x8 u;
    u.bf[0] = (__bf16)a.x; u.bf[1] = (__bf16)a.y; u.bf[2] = (__bf16)a.z; u.bf[3] = (__bf16)a.w;
    u.bf[4] = (__bf16)b.x; u.bf[5] = (__bf16)b.y; u.bf[6] = (__bf16)b.z; u.bf[7] = (__bf16)b.w;
    return u.u4;
}

// ---------------- Kernel A: QKV projection (bf16 MFMA) + fused RoPE ----------------
// grid (3, M/128): blockIdx.x = wsel (fastest -> 3 readers of same x tile adjacent),
// blockIdx.y = m-tile. Block 256 = 4 waves in 2x2, each wave 64x64 via 4x4 16x16x32 frags.
// Output: qkv planes Q|K|V, each [M][128] bf16 (RoPE applied to Q,K).
__global__ __launch_bounds__(256) void qkv_rope_kernel(
    const float* __restrict__ x,
    const float* __restrict__ Wq,
    const float* __restrict__ Wk,
    const float* __restrict__ Wv,
    const float* __restrict__ theta,
    __bf16* __restrict__ qkv, int M)
{
    // row-major [row][k] bf16, stride 40 (80 B: quad index row*5+c -> uniform spread)
    __shared__ __align__(16) unsigned short Xs[128 * 40];
    __shared__ __align__(16) unsigned short Ws[128 * 40];

    const int wsel = blockIdx.x;
    const int m0   = blockIdx.y * 128;
    const float* Wmat = (wsel == 0) ? Wq : (wsel == 1) ? Wk : Wv;
    __bf16* dst = qkv + (size_t)wsel * M * DH;

    const int tid = threadIdx.x;
    const int ln  = tid & 63;
    const int wv  = tid >> 6;
    const int wm  = (wv & 1) * 64, wn = (wv >> 1) * 64;

    // staging task mapping: 512 16B-chunks per matrix: row = tid>>2 (+64), chunk = tid&3
    const int srow0 = tid >> 2;
    const int srow1 = srow0 + 64;
    const int scol  = (tid & 3) * 8;   // fp32/bf16 element offset within 32-wide k-tile

    float4 xa0, xb0, xa1, xb1, wa0, wb0, wa1, wb1;
    {   // prefetch kc = 0
        const float* p;
        p = x    + (size_t)(m0 + srow0) * D_MODEL + scol; xa0 = *(const float4*)p; xb0 = *(const float4*)(p + 4);
        p = x    + (size_t)(m0 + srow1) * D_MODEL + scol; xa1 = *(const float4*)p; xb1 = *(const float4*)(p + 4);
        p = Wmat + (size_t)srow0 * D_MODEL + scol;        wa0 = *(const float4*)p; wb0 = *(const float4*)(p + 4);
        p = Wmat + (size_t)srow1 * D_MODEL + scol;        wa1 = *(const float4*)p; wb1 = *(const float4*)(p + 4);
    }

    f32x4 acc[4][4];
    #pragma unroll
    for (int i = 0; i < 4; ++i)
        #pragma unroll
        for (int j = 0; j < 4; ++j) acc[i][j] = (f32x4)(0.f);

    const int lo = ln & 15;
    const int hi = (ln >> 4) * 8;

    for (int kc = 0; kc < D_MODEL; kc += 32) {
        __syncthreads();
        *(uint4*)&Xs[srow0 * 40 + scol] = cvt8(xa0, xb0);
        *(uint4*)&Xs[srow1 * 40 + scol] = cvt8(xa1, xb1);
        *(uint4*)&Ws[srow0 * 40 + scol] = cvt8(wa0, wb0);
        *(uint4*)&Ws[srow1 * 40 + scol] = cvt8(wa1, wb1);
        __syncthreads();
        if (kc + 32 < D_MODEL) {   // prefetch next k-slab
            const int kn = kc + 32;
            const float* p;
            p = x    + (size_t)(m0 + srow0) * D_MODEL + kn + scol; xa0 = *(const float4*)p; xb0 = *(const float4*)(p + 4);
            p = x    + (size_t)(m0 + srow1) * D_MODEL + kn + scol; xa1 = *(const float4*)p; xb1 = *(const float4*)(p + 4);
            p = Wmat + (size_t)srow0 * D_MODEL + kn + scol;        wa0 = *(const float4*)p; wb0 = *(const float4*)(p + 4);
            p = Wmat + (size_t)srow1 * D_MODEL + kn + scol;        wa1 = *(const float4*)p; wb1 = *(const float4*)(p + 4);
        }
        bfx8 af[4], bfr[4];
        #pragma unroll
        for (int i = 0; i < 4; ++i) af[i]  = *(const bfx8*)&Xs[(wm + i * 16 + lo) * 40 + hi];
        #pragma unroll
        for (int j = 0; j < 4; ++j) bfr[j] = *(const bfx8*)&Ws[(wn + j * 16 + lo) * 40 + hi];
        #pragma unroll
        for (int i = 0; i < 4; ++i)
            #pragma unroll
            for (int j = 0; j < 4; ++j)
                acc[i][j] = __builtin_amdgcn_mfma_f32_16x16x32_bf16(af[i], bfr[j], acc[i][j], 0, 0, 0);
    }

    // Epilogue: C-layout col = ln&15 (h), row = (ln>>4)*4 + r (m). RoPE pairs are in
    // adjacent lanes -> shfl_xor(1). ref: even: e*c + o*s ; odd: o*c - e*s ; ang=(t+1)*theta[h]
    const int rbase = (ln >> 4) * 4;
    #pragma unroll
    for (int j = 0; j < 4; ++j) {
        const int h = wn + j * 16 + lo;
        const float th = (wsel < 2) ? theta[h] : 0.f;
        #pragma unroll
        for (int i = 0; i < 4; ++i) {
            #pragma unroll
            for (int r = 0; r < 4; ++r) {
                const int m = m0 + wm + i * 16 + rbase + r;
                float v = acc[i][j][r];
                float res;
                if (wsel < 2) {
                    float partner = __shfl_xor(v, 1, 64);
                    float ang = (float)((m & (T_SEQ - 1)) + 1) * th;
                    float rev = ang * 0.15915494309189535f;   // 1/(2*pi)
                    rev -= floorf(rev);
                    float s = __builtin_amdgcn_sinf(rev);     // v_sin: input in revolutions
                    float c = __builtin_amdgcn_cosf(rev);
                    res = (h & 1) ? (v * c - partner * s) : (v * c + partner * s);
                } else {
                    res = v;
                }
                dst[(size_t)m * DH + h] = (__bf16)res;
            }
        }
    }
}

// ---------------- Kernel B: MFMA flash attention ----------------
// grid (T/64, B). Block 256 = 4 waves; wave w owns q-rows q0+16w..+15.
// KT=32. K row-major in LDS; V transposed (Vt[d][k]); P via LDS (wave-private).
__global__ __launch_bounds__(256) void attn_kernel(
    const __bf16* __restrict__ qkv, float* __restrict__ out, int M)
{
    __shared__ __align__(16) unsigned short Ks[32 * 136];   // [k][d], stride 136 (17 quads)
    __shared__ __align__(16) unsigned short Vt[128 * 40];   // [d][k], stride 40 (5 quads)
    __shared__ __align__(16) unsigned short Ps[4 * 16 * 40];// per-wave P [16][40]

    const int b  = blockIdx.y;
    const int q0 = blockIdx.x * 64;
    const __bf16* Qp = qkv + (size_t)b * T_SEQ * DH;
    const __bf16* Kp = qkv + (size_t)M * DH + (size_t)b * T_SEQ * DH;
    const __bf16* Vp = qkv + 2 * (size_t)M * DH + (size_t)b * T_SEQ * DH;

    const int tid = threadIdx.x;
    const int ln  = tid & 63;
    const int wv  = tid >> 6;
    const int qbase = q0 + wv * 16;
    const int lo  = ln & 15;
    const int hi8 = (ln >> 4) * 8;

    // Q A-frags in registers for whole k-loop: lane holds Q[qbase+lo][c*32 + hi8 .. +7]
    bfx8 qf[4];
    {
        const __bf16* qrow = Qp + (size_t)(qbase + lo) * DH;
        #pragma unroll
        for (int c = 0; c < 4; ++c) qf[c] = *(const bfx8*)(qrow + c * 32 + hi8);
    }

    f32x4 O[8];
    #pragma unroll
    for (int j = 0; j < 8; ++j) O[j] = (f32x4)(0.f);
    float mst[4], lst[4];
    #pragma unroll
    for (int r = 0; r < 4; ++r) { mst[r] = -__builtin_inff(); lst[r] = 0.f; }

    const int nt = (q0 >> 5) + 2;

    // staging mappings (256 threads):
    //  K: chunk i = tid + t*256: row = i>>4 (0..31), seg = tid&15  -> coalesced
    //  V: i: k = tid&31, seg = i>>5 (0..15) -> conflict-free transposed b16 writes
    const int krow0 = tid >> 4;
    const int kseg  = tid & 15;
    const int vk    = tid & 31;
    const int vseg0 = tid >> 5;

    uint4 kreg[2], vreg[2];
    {
        kreg[0] = *(const uint4*)(Kp + (size_t)krow0 * DH + kseg * 8);
        kreg[1] = *(const uint4*)(Kp + (size_t)(krow0 + 16) * DH + kseg * 8);
        vreg[0] = *(const uint4*)(Vp + (size_t)vk * DH + vseg0 * 8);
        vreg[1] = *(const uint4*)(Vp + (size_t)vk * DH + (vseg0 + 8) * 8);
    }

    unsigned short* Pw = &Ps[wv * 640];

    for (int kt = 0; kt < nt; ++kt) {
        const int k0 = kt * 32;
        __syncthreads();   // previous tile's frag reads done
        *(uint4*)&Ks[krow0 * 136 + kseg * 8]        = kreg[0];
        *(uint4*)&Ks[(krow0 + 16) * 136 + kseg * 8] = kreg[1];
        {
            U16x8 u;
            u.u4 = vreg[0];
            #pragma unroll
            for (int e = 0; e < 8; ++e) Vt[(vseg0 * 8 + e) * 40 + vk] = u.us[e];
            u.u4 = vreg[1];
            #pragma unroll
            for (int e = 0; e < 8; ++e) Vt[((vseg0 + 8) * 8 + e) * 40 + vk] = u.us[e];
        }
        __syncthreads();
        if (kt + 1 < nt) {   // prefetch next tile
            const int kn = k0 + 32;
            kreg[0] = *(const uint4*)(Kp + (size_t)(kn + krow0) * DH + kseg * 8);
            kreg[1] = *(const uint4*)(Kp + (size_t)(kn + krow0 + 16) * DH + kseg * 8);
            vreg[0] = *(const uint4*)(Vp + (size_t)(kn + vk) * DH + vseg0 * 8);
            vreg[1] = *(const uint4*)(Vp + (size_t)(kn + vk) * DH + (vseg0 + 8) * 8);
        }

        if (k0 <= qbase + 15) {   // wave-uniform: this wave has unmasked cols in tile
            // ---- S = Q K^T (two 16-col n-frags) ----
            f32x4 s4[2];
            s4[0] = (f32x4)(0.f); s4[1] = (f32x4)(0.f);
            #pragma unroll
            for (int c = 0; c < 4; ++c) {
                bfx8 kf0 = *(const bfx8*)&Ks[lo * 136 + c * 32 + hi8];
                bfx8 kf1 = *(const bfx8*)&Ks[(16 + lo) * 136 + c * 32 + hi8];
                s4[0] = __builtin_amdgcn_mfma_f32_16x16x32_bf16(qf[c], kf0, s4[0], 0, 0, 0);
                s4[1] = __builtin_amdgcn_mfma_f32_16x16x32_bf16(qf[c], kf1, s4[1], 0, 0, 0);
            }
            float sc[2][4];
            #pragma unroll
            for (int j = 0; j < 2; ++j)
                #pragma unroll
                for (int r = 0; r < 4; ++r) sc[j][r] = s4[j][r] * 0.03125f;  // 1024^-0.5

            if (k0 + 31 > qbase) {   // diagonal tile: causal mask
                #pragma unroll
                for (int j = 0; j < 2; ++j)
                    #pragma unroll
                    for (int r = 0; r < 4; ++r) {
                        const int col = k0 + j * 16 + lo;
                        const int row = qbase + (ln >> 4) * 4 + r;
                        if (col > row) sc[j][r] = -__builtin_inff();
                    }
            }

            // ---- online softmax (rows live in 16-lane shuffle groups) ----
            float rm[4];
            #pragma unroll
            for (int r = 0; r < 4; ++r) rm[r] = fmaxf(sc[0][r], sc[1][r]);
            #pragma unroll
            for (int off = 1; off < 16; off <<= 1)
                #pragma unroll
                for (int r = 0; r < 4; ++r) rm[r] = fmaxf(rm[r], __shfl_xor(rm[r], off, 64));
            float alpha[4];
            #pragma unroll
            for (int r = 0; r < 4; ++r) {
                float mn = fmaxf(mst[r], rm[r]);
                alpha[r] = __expf(mst[r] - mn);
                mst[r] = mn;
            }
            float ps[4];
            #pragma unroll
            for (int r = 0; r < 4; ++r) ps[r] = 0.f;
            #pragma unroll
            for (int j = 0; j < 2; ++j)
                #pragma unroll
                for (int r = 0; r < 4; ++r) {
                    float p = __expf(sc[j][r] - mst[r]);
                    ps[r] += p;
                    *(__bf16*)&Pw[((ln >> 4) * 4 + r) * 40 + j * 16 + lo] = (__bf16)p;
                }
            #pragma unroll
            for (int off = 1; off < 16; off <<= 1)
                #pragma unroll
                for (int r = 0; r < 4; ++r) ps[r] += __shfl_xor(ps[r], off, 64);
            #pragma unroll
            for (int r = 0; r < 4; ++r) lst[r] = lst[r] * alpha[r] + ps[r];
            #pragma unroll
            for (int j = 0; j < 8; ++j)
                #pragma unroll
                for (int r = 0; r < 4; ++r) O[j][r] *= alpha[r];

            // ---- O += P V ---- (P A-frag from LDS; Vt B-frags)
            bfx8 pf = *(const bfx8*)&Pw[lo * 40 + hi8];
            #pragma unroll
            for (int j = 0; j < 8; ++j) {
                bfx8 vf = *(const bfx8*)&Vt[(j * 16 + lo) * 40 + hi8];
                O[j] = __builtin_amdgcn_mfma_f32_16x16x32_bf16(pf, vf, O[j], 0, 0, 0);
            }
        }
    }

    float rl[4];
    #pragma unroll
    for (int r = 0; r < 4; ++r) rl[r] = 1.f / lst[r];
    #pragma unroll
    for (int j = 0; j < 8; ++j)
        #pragma unroll
        for (int r = 0; r < 4; ++r)
            out[((size_t)b * T_SEQ + qbase + (ln >> 4) * 4 + r) * DH + j * 16 + lo] = O[j][r] * rl[r];
}

extern "C" void kernel_launch(void* const* d_in, const int* in_sizes, int n_in,
                              void* d_out, int out_size, void* d_ws, size_t ws_size,
                              hipStream_t stream) {
    const float* x     = (const float*)d_in[0];
    const float* Wq    = (const float*)d_in[1];
    const float* Wk    = (const float*)d_in[2];
    const float* Wv    = (const float*)d_in[3];
    const float* theta = (const float*)d_in[4];
    float* out = (float*)d_out;
    __bf16* qkv = (__bf16*)d_ws;   // 3 * M * 128 * 2 B = 6.3 MB

    const int M = in_sizes[0] / D_MODEL;   // B*T = 8192
    const int B = M / T_SEQ;               // 4

    qkv_rope_kernel<<<dim3(3, M / 128), 256, 0, stream>>>(x, Wq, Wk, Wv, theta, qkv, M);
    attn_kernel<<<dim3(T_SEQ / 64, B), 256, 0, stream>>>(qkv, out, M);
}

// Round 3
// 163.475 us; speedup vs baseline: 3.0568x; 1.3129x over previous
//
#include <hip/hip_runtime.h>
#include <math.h>

#define T_SEQ 2048
#define D_MODEL 1024
#define DH 128
#define CHUNK 256
#define SLOTS 144   // sum over 32 q-tiles of ceil((qt*64+64)/256), per batch

typedef __bf16 bfx8 __attribute__((ext_vector_type(8)));
typedef float f32x4 __attribute__((ext_vector_type(4)));

union U16x8 { uint4 u4; unsigned int ui[4]; unsigned short us[8]; __bf16 bf[8]; bfx8 v; };

__device__ inline uint4 cvt8u(float4 a, float4 b) {
    U16x8 u;
    u.bf[0] = (__bf16)a.x; u.bf[1] = (__bf16)a.y; u.bf[2] = (__bf16)a.z; u.bf[3] = (__bf16)a.w;
    u.bf[4] = (__bf16)b.x; u.bf[5] = (__bf16)b.y; u.bf[6] = (__bf16)b.z; u.bf[7] = (__bf16)b.w;
    return u.u4;
}
__device__ inline bfx8 cvt8bf(float4 a, float4 b) {
    U16x8 u; u.u4 = cvt8u(a, b); return u.v;
}

// ---------------- Kernel A: QKV projection (bf16 MFMA) + fused RoPE ----------------
// grid (3, M/64). Block 256 = 4 waves; wave wv owns rows m0+wv*16..+15, all 128 N.
// W double-buffered in LDS (1 barrier/slab); A direct global->reg->bf16 (no LDS).
__global__ __launch_bounds__(256) void qkv_rope_kernel(
    const float* __restrict__ x,
    const float* __restrict__ Wq,
    const float* __restrict__ Wk,
    const float* __restrict__ Wv,
    const float* __restrict__ theta,
    __bf16* __restrict__ qkv, int M)
{
    __shared__ __align__(16) unsigned short Wsh[2][128 * 40];  // [row][k] bf16, stride 40

    const int wsel = blockIdx.x;
    const int m0   = blockIdx.y * 64;
    const float* Wmat = (wsel == 0) ? Wq : (wsel == 1) ? Wk : Wv;
    __bf16* dst = qkv + (size_t)wsel * M * DH;

    const int tid = threadIdx.x;
    const int ln  = tid & 63;
    const int wv  = tid >> 6;
    const int lo  = ln & 15;
    const int hi8 = (ln >> 4) * 8;

    // W staging mapping: thread -> row=tid>>1 (0..127), 16-col half
    const int wrow = tid >> 1;
    const int wcol = (tid & 1) * 16;
    const float* wp = Wmat + (size_t)wrow * D_MODEL + wcol;
    const float* ap = x + (size_t)(m0 + wv * 16 + lo) * D_MODEL + hi8;

    float4 wr0 = *(const float4*)(wp);
    float4 wr1 = *(const float4*)(wp + 4);
    float4 wr2 = *(const float4*)(wp + 8);
    float4 wr3 = *(const float4*)(wp + 12);
    float4 ar0 = *(const float4*)(ap);
    float4 ar1 = *(const float4*)(ap + 4);

    *(uint4*)&Wsh[0][wrow * 40 + wcol]     = cvt8u(wr0, wr1);
    *(uint4*)&Wsh[0][wrow * 40 + wcol + 8] = cvt8u(wr2, wr3);
    __syncthreads();

    f32x4 acc[8];
    #pragma unroll
    for (int j = 0; j < 8; ++j) acc[j] = (f32x4)(0.f);

    for (int s = 0; s < 32; ++s) {
        const unsigned short* B = Wsh[s & 1];
        unsigned short* Bn = Wsh[(s & 1) ^ 1];
        float4 nw0, nw1, nw2, nw3, na0, na1;
        if (s < 31) {
            const float* q = wp + (s + 1) * 32;
            nw0 = *(const float4*)(q);  nw1 = *(const float4*)(q + 4);
            nw2 = *(const float4*)(q + 8); nw3 = *(const float4*)(q + 12);
            const float* q2 = ap + (s + 1) * 32;
            na0 = *(const float4*)(q2); na1 = *(const float4*)(q2 + 4);
        }
        bfx8 af = cvt8bf(ar0, ar1);
        #pragma unroll
        for (int j = 0; j < 8; ++j) {
            bfx8 bf = *(const bfx8*)&B[(j * 16 + lo) * 40 + hi8];
            acc[j] = __builtin_amdgcn_mfma_f32_16x16x32_bf16(af, bf, acc[j], 0, 0, 0);
        }
        if (s < 31) {
            *(uint4*)&Bn[wrow * 40 + wcol]     = cvt8u(nw0, nw1);
            *(uint4*)&Bn[wrow * 40 + wcol + 8] = cvt8u(nw2, nw3);
            ar0 = na0; ar1 = na1;
        }
        __syncthreads();
    }

    // RoPE epilogue. C-layout: col=ln&15, row=(ln>>4)*4+r. Pairs in adjacent lanes.
    const int rbase = (ln >> 4) * 4;
    #pragma unroll
    for (int j = 0; j < 8; ++j) {
        const int h = j * 16 + lo;
        const float th = (wsel < 2) ? theta[h] : 0.f;
        #pragma unroll
        for (int r = 0; r < 4; ++r) {
            const int m = m0 + wv * 16 + rbase + r;
            float v = acc[j][r];
            float partner = __shfl_xor(v, 1, 64);
            float re, ro;
            if (wsel < 2) {
                float e = (h & 1) ? partner : v;
                float o = (h & 1) ? v : partner;
                float ang = (float)((m & (T_SEQ - 1)) + 1) * th;
                float rev = ang * 0.15915494309189535f;  // 1/(2*pi)
                rev -= floorf(rev);
                float sn = __builtin_amdgcn_sinf(rev);
                float cs = __builtin_amdgcn_cosf(rev);
                re = e * cs + o * sn;
                ro = o * cs - e * sn;
            } else {
                re = (h & 1) ? partner : v;
                ro = (h & 1) ? v : partner;
            }
            if (!(h & 1)) {   // even lane packs (even,odd) -> one dword store
                U16x8 u;
                u.bf[0] = (__bf16)re; u.bf[1] = (__bf16)ro;
                *(unsigned int*)&dst[(size_t)m * DH + h] = u.ui[0];
            }
        }
    }
}

// ---------------- Kernel B: split-K MFMA flash attention (partials) ----------------
// grid (32, 8, B): qt = x (fastest: consecutive blocks share KV chunk), c = y, b = z.
// Block: 64 q-rows (4 waves x 16), k-chunk of <=256 cols (<=8 tiles of 32).
__global__ __launch_bounds__(256) void attn_partial_kernel(
    const __bf16* __restrict__ qkv,
    __bf16* __restrict__ Op, float* __restrict__ Ml, float* __restrict__ Ll, int M)
{
    const int qt = blockIdx.x, c = blockIdx.y, b = blockIdx.z;
    const int q0 = qt * 64;
    const int kstart = c * CHUNK;
    if (kstart > q0) return;                          // chunk beyond causal end
    const int nt = min(8, (q0 + 64 - kstart) >> 5);   // k-tiles this block
    const int g = qt >> 2;
    const int slot = 2 * g * (g + 1) + (qt & 3) * (g + 1) + c;
    const size_t sb = (size_t)b * SLOTS + slot;

    __shared__ __align__(16) unsigned short Ks[32 * 136];
    __shared__ __align__(16) unsigned short Vt[128 * 40];
    __shared__ __align__(16) unsigned short Ps[4 * 16 * 40];

    const __bf16* Qp = qkv + (size_t)b * T_SEQ * DH;
    const __bf16* Kp = qkv + (size_t)M * DH + (size_t)b * T_SEQ * DH;
    const __bf16* Vp = qkv + 2 * (size_t)M * DH + (size_t)b * T_SEQ * DH;

    const int tid = threadIdx.x;
    const int ln  = tid & 63;
    const int wv  = tid >> 6;
    const int qbase = q0 + wv * 16;
    const int lo  = ln & 15;
    const int hi8 = (ln >> 4) * 8;

    bfx8 qf[4];
    {
        const __bf16* qrow = Qp + (size_t)(qbase + lo) * DH;
        #pragma unroll
        for (int cc = 0; cc < 4; ++cc) qf[cc] = *(const bfx8*)(qrow + cc * 32 + hi8);
    }

    f32x4 O[8];
    #pragma unroll
    for (int j = 0; j < 8; ++j) O[j] = (f32x4)(0.f);
    float mst[4], lst[4];
    #pragma unroll
    for (int r = 0; r < 4; ++r) { mst[r] = -__builtin_inff(); lst[r] = 0.f; }

    const int krow0 = tid >> 4;
    const int kseg  = tid & 15;
    const int vk    = tid & 31;
    const int vseg0 = tid >> 5;

    uint4 kreg[2], vreg[2];
    kreg[0] = *(const uint4*)(Kp + (size_t)(kstart + krow0) * DH + kseg * 8);
    kreg[1] = *(const uint4*)(Kp + (size_t)(kstart + krow0 + 16) * DH + kseg * 8);
    vreg[0] = *(const uint4*)(Vp + (size_t)(kstart + vk) * DH + vseg0 * 8);
    vreg[1] = *(const uint4*)(Vp + (size_t)(kstart + vk) * DH + (vseg0 + 8) * 8);

    unsigned short* Pw = &Ps[wv * 640];

    for (int kt = 0; kt < nt; ++kt) {
        const int k0 = kstart + kt * 32;
        __syncthreads();
        *(uint4*)&Ks[krow0 * 136 + kseg * 8]        = kreg[0];
        *(uint4*)&Ks[(krow0 + 16) * 136 + kseg * 8] = kreg[1];
        {
            U16x8 u;
            u.u4 = vreg[0];
            #pragma unroll
            for (int e = 0; e < 8; ++e) Vt[(vseg0 * 8 + e) * 40 + vk] = u.us[e];
            u.u4 = vreg[1];
            #pragma unroll
            for (int e = 0; e < 8; ++e) Vt[((vseg0 + 8) * 8 + e) * 40 + vk] = u.us[e];
        }
        __syncthreads();
        if (kt + 1 < nt) {
            const int kn = k0 + 32;
            kreg[0] = *(const uint4*)(Kp + (size_t)(kn + krow0) * DH + kseg * 8);
            kreg[1] = *(const uint4*)(Kp + (size_t)(kn + krow0 + 16) * DH + kseg * 8);
            vreg[0] = *(const uint4*)(Vp + (size_t)(kn + vk) * DH + vseg0 * 8);
            vreg[1] = *(const uint4*)(Vp + (size_t)(kn + vk) * DH + (vseg0 + 8) * 8);
        }

        if (k0 <= qbase + 15) {
            f32x4 s4[2];
            s4[0] = (f32x4)(0.f); s4[1] = (f32x4)(0.f);
            #pragma unroll
            for (int cc = 0; cc < 4; ++cc) {
                bfx8 kf0 = *(const bfx8*)&Ks[lo * 136 + cc * 32 + hi8];
                bfx8 kf1 = *(const bfx8*)&Ks[(16 + lo) * 136 + cc * 32 + hi8];
                s4[0] = __builtin_amdgcn_mfma_f32_16x16x32_bf16(qf[cc], kf0, s4[0], 0, 0, 0);
                s4[1] = __builtin_amdgcn_mfma_f32_16x16x32_bf16(qf[cc], kf1, s4[1], 0, 0, 0);
            }
            float sc[2][4];
            #pragma unroll
            for (int j = 0; j < 2; ++j)
                #pragma unroll
                for (int r = 0; r < 4; ++r) sc[j][r] = s4[j][r] * 0.03125f;

            if (k0 + 31 > qbase) {
                #pragma unroll
                for (int j = 0; j < 2; ++j)
                    #pragma unroll
                    for (int r = 0; r < 4; ++r) {
                        const int col = k0 + j * 16 + lo;
                        const int row = qbase + (ln >> 4) * 4 + r;
                        if (col > row) sc[j][r] = -__builtin_inff();
                    }
            }

            float rm[4];
            #pragma unroll
            for (int r = 0; r < 4; ++r) rm[r] = fmaxf(sc[0][r], sc[1][r]);
            #pragma unroll
            for (int off = 1; off < 16; off <<= 1)
                #pragma unroll
                for (int r = 0; r < 4; ++r) rm[r] = fmaxf(rm[r], __shfl_xor(rm[r], off, 64));
            float alpha[4];
            #pragma unroll
            for (int r = 0; r < 4; ++r) {
                float mn = fmaxf(mst[r], rm[r]);
                alpha[r] = __expf(mst[r] - mn);
                mst[r] = mn;
            }
            float ps[4];
            #pragma unroll
            for (int r = 0; r < 4; ++r) ps[r] = 0.f;
            #pragma unroll
            for (int j = 0; j < 2; ++j)
                #pragma unroll
                for (int r = 0; r < 4; ++r) {
                    float p = __expf(sc[j][r] - mst[r]);
                    ps[r] += p;
                    *(__bf16*)&Pw[((ln >> 4) * 4 + r) * 40 + j * 16 + lo] = (__bf16)p;
                }
            #pragma unroll
            for (int off = 1; off < 16; off <<= 1)
                #pragma unroll
                for (int r = 0; r < 4; ++r) ps[r] += __shfl_xor(ps[r], off, 64);
            #pragma unroll
            for (int r = 0; r < 4; ++r) lst[r] = lst[r] * alpha[r] + ps[r];
            #pragma unroll
            for (int j = 0; j < 8; ++j)
                #pragma unroll
                for (int r = 0; r < 4; ++r) O[j][r] *= alpha[r];

            bfx8 pf = *(const bfx8*)&Pw[lo * 40 + hi8];
            #pragma unroll
            for (int j = 0; j < 8; ++j) {
                bfx8 vf = *(const bfx8*)&Vt[(j * 16 + lo) * 40 + hi8];
                O[j] = __builtin_amdgcn_mfma_f32_16x16x32_bf16(pf, vf, O[j], 0, 0, 0);
            }
        }
    }

    // store partials: unnormalized O (bf16, packed dword stores) + m,l (f32)
    const int rbase = (ln >> 4) * 4;
    __bf16* ob = Op + sb * (64 * 128);
    #pragma unroll
    for (int j = 0; j < 8; ++j) {
        const int col = j * 16 + lo;
        #pragma unroll
        for (int r = 0; r < 4; ++r) {
            float v = O[j][r];
            float partner = __shfl_xor(v, 1, 64);
            if (!(col & 1)) {
                U16x8 u;
                u.bf[0] = (__bf16)v; u.bf[1] = (__bf16)partner;
                *(unsigned int*)&ob[(wv * 16 + rbase + r) * DH + col] = u.ui[0];
            }
        }
    }
    if (lo == 0) {
        #pragma unroll
        for (int r = 0; r < 4; ++r) {
            Ml[sb * 64 + wv * 16 + rbase + r] = mst[r];
            Ll[sb * 64 + wv * 16 + rbase + r] = lst[r];
        }
    }
}

// ---------------- Kernel C: merge partials ----------------
// grid (32, B, 2). Block 256: row = tid>>2 (0..63), 16 cols per thread.
__global__ __launch_bounds__(256) void attn_merge_kernel(
    const __bf16* __restrict__ Op, const float* __restrict__ Ml,
    const float* __restrict__ Ll, float* __restrict__ out)
{
    const int qt = blockIdx.x, b = blockIdx.y, ch = blockIdx.z;
    const int q0 = qt * 64;
    const int g = qt >> 2;
    const int nc = g + 1;
    const size_t sb0 = (size_t)b * SLOTS + 2 * g * (g + 1) + (qt & 3) * (g + 1);

    const int row = threadIdx.x >> 2;
    const int cg  = ch * 64 + (threadIdx.x & 3) * 16;

    float mmax = -__builtin_inff();
    for (int cc = 0; cc < nc; ++cc)
        mmax = fmaxf(mmax, Ml[(sb0 + cc) * 64 + row]);

    float acc[16];
    #pragma unroll
    for (int e = 0; e < 16; ++e) acc[e] = 0.f;
    float lsum = 0.f;

    for (int cc = 0; cc < nc; ++cc) {
        const float w = __expf(Ml[(sb0 + cc) * 64 + row] - mmax);
        lsum += w * Ll[(sb0 + cc) * 64 + row];
        const __bf16* p = Op + (sb0 + cc) * (64 * 128) + row * 128 + cg;
        U16x8 u0, u1;
        u0.u4 = *(const uint4*)p;
        u1.u4 = *(const uint4*)(p + 8);
        #pragma unroll
        for (int e = 0; e < 8; ++e) acc[e]     = fmaf(w, (float)u0.bf[e], acc[e]);
        #pragma unroll
        for (int e = 0; e < 8; ++e) acc[8 + e] = fmaf(w, (float)u1.bf[e], acc[8 + e]);
    }

    const float inv = 1.f / lsum;
    float* op = out + ((size_t)b * T_SEQ + q0 + row) * DH + cg;
    #pragma unroll
    for (int v4 = 0; v4 < 4; ++v4)
        *(float4*)(op + v4 * 4) = make_float4(acc[v4*4] * inv, acc[v4*4+1] * inv,
                                              acc[v4*4+2] * inv, acc[v4*4+3] * inv);
}

extern "C" void kernel_launch(void* const* d_in, const int* in_sizes, int n_in,
                              void* d_out, int out_size, void* d_ws, size_t ws_size,
                              hipStream_t stream) {
    const float* x     = (const float*)d_in[0];
    const float* Wq    = (const float*)d_in[1];
    const float* Wk    = (const float*)d_in[2];
    const float* Wv    = (const float*)d_in[3];
    const float* theta = (const float*)d_in[4];
    float* out = (float*)d_out;

    const int M = in_sizes[0] / D_MODEL;   // B*T = 8192
    const int B = M / T_SEQ;               // 4

    // ws layout: qkv bf16 | Op bf16 | Ml f32 | Ll f32  (~16.0 MB total)
    __bf16* qkv = (__bf16*)d_ws;
    const size_t qkvBytes = (size_t)3 * M * DH * 2;                  // 6,291,456
    __bf16* Op = (__bf16*)((char*)d_ws + qkvBytes);
    const size_t opBytes = (size_t)B * SLOTS * 64 * 128 * 2;         // 9,437,184
    float* Ml = (float*)((char*)d_ws + qkvBytes + opBytes);
    const size_t mlBytes = (size_t)B * SLOTS * 64 * 4;               // 147,456
    float* Ll = (float*)((char*)d_ws + qkvBytes + opBytes + mlBytes);

    qkv_rope_kernel<<<dim3(3, M / 64), 256, 0, stream>>>(x, Wq, Wk, Wv, theta, qkv, M);
    attn_partial_kernel<<<dim3(T_SEQ / 64, T_SEQ / CHUNK, B), 256, 0, stream>>>(qkv, Op, Ml, Ll, M);
    attn_merge_kernel<<<dim3(T_SEQ / 64, B, 2), 256, 0, stream>>>(Op, Ml, Ll, out);
}